// Round 14
// baseline (542.665 us; speedup 1.0000x reference)
//
#include <hip/hip_runtime.h>
#include <math.h>

#define N_ 2
#define A_ 5
#define C_ 12
#define H_ 256
#define G_ 512
// out = 4 * ifft_ortho(K * fft_ortho(...)) ==> 4/(512*512) on unnormalized FFTs
#define SCALE_ (4.0f / 262144.0f)
#define OUTF_ 655360       // out = fp32 REAL part, [2,5,256,256]
#define HALFF_ 327680      // per-n float count
#define IMGC_ 131072       // 512*256 complex: one spectral half-plane (h2 elems)
#define NCG_ 4             // C2 c-groups (3 c each)

// ---- fp16-pair scratch ------------------------------------------------------
struct __attribute__((aligned(4))) h2 { _Float16 x, y; };
struct __attribute__((aligned(8))) h2x2 { _Float16 x0, y0, x1, y1; };
__device__ __forceinline__ float2 ld2(const h2* p, size_t i) {
    h2 v = p[i]; return make_float2((float)v.x, (float)v.y);
}
__device__ __forceinline__ void st2(h2* p, size_t i, float2 v) {
    float x = fminf(fmaxf(v.x, -60000.f), 60000.f);   // never store inf
    float y = fminf(fmaxf(v.y, -60000.f), 60000.f);
    h2 o; o.x = (_Float16)x; o.y = (_Float16)y; p[i] = o;
}

__device__ __forceinline__ float2 cmul(float2 a, float2 b) {
    return make_float2(a.x * b.x - a.y * b.y, a.x * b.y + a.y * b.x);
}

// ---- float4 = two adjacent complexes helpers --------------------------------
__device__ __forceinline__ float4 qadd(float4 a, float4 b) {
    return make_float4(a.x + b.x, a.y + b.y, a.z + b.z, a.w + b.w);
}
__device__ __forceinline__ float4 qsub(float4 a, float4 b) {
    return make_float4(a.x - b.x, a.y - b.y, a.z - b.z, a.w - b.w);
}
__device__ __forceinline__ float4 qmul(float4 a, float4 w) {   // per-complex a*w
    return make_float4(a.x * w.x - a.y * w.y, a.x * w.y + a.y * w.x,
                       a.z * w.z - a.w * w.w, a.z * w.w + a.w * w.z);
}
__device__ __forceinline__ float4 qmulc(float4 a, float4 w) {  // per-complex a*conj(w)
    return make_float4(a.x * w.x + a.y * w.y, a.y * w.x - a.x * w.y,
                       a.z * w.z + a.w * w.w, a.w * w.z - a.z * w.w);
}
// f4-index bank swizzle: bijective within 8-blocks, kills stride-4/16 conflicts
__device__ __forceinline__ int PHI(int i) { return i ^ ((i >> 3) & 7); }

// Per-stage twiddle tables, float2 twS[512] (works for any blockDim >= 256).
__device__ __forceinline__ void build_twS(float2* twS, int t) {
    if (t < 256) {
        float s, c;
        sincosf(-6.283185307179586f * (float)t * (1.0f / 512.0f), &s, &c);
        twS[t] = make_float2(c, s);
    }
    __syncthreads();
    int off = 256;
    #pragma unroll
    for (int sh = 1; sh <= 8; sh++) {
        int sz = 256 >> sh;
        if (t < sz) twS[off + t] = twS[t << sh];
        off += sz;
    }
    __syncthreads();
}

// ---- radix-4 f4-paired LDS quads (proven R5 form) ---------------------------
__device__ __forceinline__ void fwd_quad(float4* D, const float4* tw4,
                                         int bt, int M4, int offA4) {
    int jf = bt & (M4 - 1);
    int f0 = ((bt & ~(M4 - 1)) << 2) | jf;
    float4 x0 = D[PHI(f0)],          x1 = D[PHI(f0 + M4)];
    float4 x2 = D[PHI(f0 + 2 * M4)], x3 = D[PHI(f0 + 3 * M4)];
    float4 tA  = tw4[offA4 + jf];
    float4 tA2 = tw4[offA4 + M4 + jf];
    float4 tB  = tw4[offA4 + 2 * M4 + jf];
    float4 u0 = qadd(x0, x2), v0 = qmul(qsub(x0, x2), tA);
    float4 u1 = qadd(x1, x3), v1 = qmul(qsub(x1, x3), tA2);
    D[PHI(f0)]          = qadd(u0, u1);
    D[PHI(f0 + M4)]     = qmul(qsub(u0, u1), tB);
    D[PHI(f0 + 2 * M4)] = qadd(v0, v1);
    D[PHI(f0 + 3 * M4)] = qmul(qsub(v0, v1), tB);
}
// First fwd stage-pair with x0 = x3 = 0 (centered zero-pad). Bit-identical
// to fwd_quad on zero-filled input.
__device__ __forceinline__ void fwd_quad0(float4* D, const float4* tw4, int bt) {
    int f0 = bt;   // jf = bt, M4 = 64
    float4 x1 = D[PHI(f0 + 64)];
    float4 x2 = D[PHI(f0 + 128)];
    float4 tA  = tw4[f0];
    float4 tA2 = tw4[64 + f0];
    float4 tB  = tw4[128 + f0];
    float4 zero = make_float4(0.f, 0.f, 0.f, 0.f);
    float4 v0 = qmul(qsub(zero, x2), tA);
    float4 v1 = qmul(x1, tA2);
    D[PHI(f0)]       = qadd(x2, x1);
    D[PHI(f0 + 64)]  = qmul(qsub(x2, x1), tB);
    D[PHI(f0 + 128)] = qadd(v0, v1);
    D[PHI(f0 + 192)] = qmul(qsub(v0, v1), tB);
}
__device__ __forceinline__ void inv_quad(float4* D, const float4* tw4,
                                         int bt, int M2, int offM4, int off2M4) {
    int jf = bt & (M2 - 1);
    int f0 = ((bt & ~(M2 - 1)) << 2) | jf;
    float4 x0 = D[PHI(f0)],          x1 = D[PHI(f0 + M2)];
    float4 x2 = D[PHI(f0 + 2 * M2)], x3 = D[PHI(f0 + 3 * M2)];
    float4 wA  = tw4[offM4 + jf];
    float4 wB0 = tw4[off2M4 + jf];
    float4 wB1 = tw4[off2M4 + M2 + jf];
    float4 t1 = qmulc(x1, wA), t3 = qmulc(x3, wA);
    float4 u0 = qadd(x0, t1), u1 = qsub(x0, t1);
    float4 u2 = qadd(x2, t3), u3 = qsub(x2, t3);
    float4 s2 = qmulc(u2, wB0), s3 = qmulc(u3, wB1);
    D[PHI(f0)]          = qadd(u0, s2);
    D[PHI(f0 + M2)]     = qadd(u1, s3);
    D[PHI(f0 + 2 * M2)] = qsub(u0, s2);
    D[PHI(f0 + 3 * M2)] = qsub(u1, s3);
}
// Last inv stage-pair writing ONLY the crop window f4 [64,192).
__device__ __forceinline__ void inv_quad_crop(float4* D, const float4* tw4,
                                              int bt) {
    int f0 = bt;   // jf = bt, M2 = 64
    float4 x0 = D[PHI(f0)],       x1 = D[PHI(f0 + 64)];
    float4 x2 = D[PHI(f0 + 128)], x3 = D[PHI(f0 + 192)];
    float4 wA  = tw4[128 + f0];
    float4 wB0 = tw4[f0];
    float4 wB1 = tw4[64 + f0];
    float4 t1 = qmulc(x1, wA), t3 = qmulc(x3, wA);
    float4 u0 = qadd(x0, t1), u1 = qsub(x0, t1);
    float4 u2 = qadd(x2, t3), u3 = qsub(x2, t3);
    float4 s2 = qmulc(u2, wB0), s3 = qmulc(u3, wB1);
    D[PHI(f0 + 64)]  = qadd(u1, s3);
    D[PHI(f0 + 128)] = qsub(u0, s2);
}

// ---- legacy single-array radix-2 FFTs (fallback path only) ------------------
__device__ void fft512_dif(float2* d, const float2* twS, int t) {
    int off = 0;
    #pragma unroll
    for (int m = 256; m >= 1; m >>= 1) {
        if (m >= 64) __syncthreads();
        else __builtin_amdgcn_wave_barrier();
        int j = t & (m - 1);
        int p = ((t & ~(m - 1)) << 1) | j;
        int q = p + m;
        float2 a = d[p], b = d[q];
        d[p] = make_float2(a.x + b.x, a.y + b.y);
        float2 s = make_float2(a.x - b.x, a.y - b.y);
        d[q] = cmul(s, twS[off + j]);
        off += m;
    }
    __syncthreads();
}
__device__ void ifft512_dit(float2* d, const float2* twS, int t) {
    int off = 510;
    #pragma unroll
    for (int m = 1; m <= 256; m <<= 1) {
        if (m == 1 || m >= 128) __syncthreads();
        else __builtin_amdgcn_wave_barrier();
        int j = t & (m - 1);
        int p = ((t & ~(m - 1)) << 1) | j;
        int q = p + m;
        float2 w = twS[off + j];
        w.y = -w.y;
        float2 b = cmul(d[q], w);
        float2 a = d[p];
        d[p] = make_float2(a.x + b.x, a.y + b.y);
        d[q] = make_float2(a.x - b.x, a.y - b.y);
        off -= (m << 1);
    }
    __syncthreads();
}

// ===========================================================================
// FAST-PATH BODIES
// ===========================================================================

// R body: Krev[p][h][jw] = K[p][h][brev9(jw)], p = b*5+a.
__device__ __forceinline__ void r_body(int blk, const float* __restrict__ kr,
                                       const float* __restrict__ ki, h2* Krev,
                                       int t) {
    int p = blk >> 9;
    int h = blk & 511;
    size_t base = ((size_t)p * G_ + h) * G_;
    int j0 = __brev((unsigned)t) >> 23;
    int j1 = __brev((unsigned)(t + 256)) >> 23;
    st2(Krev, base + t,       make_float2(kr[base + j0], ki[base + j0]));
    st2(Krev, base + t + 256, make_float2(kr[base + j1], ki[base + j1]));
}

// A2 body (single a per block): block = (nl,a,c,oct). x*mps, pad h (implicit;
// fwd_quad0 skips zeros), fwd FFT_h, transposed store to P[nl,c,a].
// blk in [0, nspan*12*5*32).
__device__ __forceinline__ void a2_body(int blk,
    const float* __restrict__ xr, const float* __restrict__ xi,
    const float* __restrict__ mr, const float* __restrict__ mi,
    h2* P, int n0, int t, float2* twS, float4 (*rows4)[262]) {
    int oct = blk & 31;
    int a   = (blk >> 5) % 5;
    int rest = blk / 160;
    int c  = rest % 12;
    int nl = rest / 12;
    int n  = n0 + nl;
    build_twS(twS, t);
    const float4* tw4 = (const float4*)twS;

    int r = t & 7;
    int wc = oct * 8 + r;
    float2* rowf2 = (float2*)&rows4[r][0];
    #pragma unroll
    for (int k = 0; k < 8; k++) {
        int h = (t >> 3) + 32 * k;
        size_t xo = (((size_t)n * A_ + a) * H_ + h) * H_ + wc;
        size_t mo = (((size_t)c) * H_ + h) * H_ + wc;
        float xr_ = xr[xo], xi_ = xi[xo];
        float mr_ = mr[mo], mi_ = mi[mo];
        int e = h + 128;
        rowf2[2 * PHI(e >> 1) + (e & 1)] =
            make_float2(xr_ * mr_ - xi_ * mi_, xr_ * mi_ + xi_ * mr_);
        // pad zeros not written: fwd_quad0 never reads them
    }
    __syncthreads();

    int wv = t >> 6, ln = t & 63;
    float4* d0 = &rows4[2 * wv][0];
    float4* d1 = &rows4[2 * wv + 1][0];
    fwd_quad0(d0, tw4, ln);         fwd_quad0(d1, tw4, ln);
    __builtin_amdgcn_wave_barrier();
    fwd_quad(d0, tw4, ln, 16, 192); fwd_quad(d1, tw4, ln, 16, 192);
    __builtin_amdgcn_wave_barrier();
    fwd_quad(d0, tw4, ln, 4, 240);  fwd_quad(d1, tw4, ln, 4, 240);
    __builtin_amdgcn_wave_barrier();
    fwd_quad(d0, tw4, ln, 1, 252);  fwd_quad(d1, tw4, ln, 1, 252);
    __syncthreads();

    h2* Pp = P + (size_t)((nl * 12 + c) * 5 + a) * IMGC_;
    #pragma unroll
    for (int k = 0; k < 16; k++) {
        int jh = k * 32 + (t >> 3);
        float4 v = rows4[r][PHI(jh >> 1)];
        float2 res = (jh & 1) ? make_float2(v.x - v.z, v.y - v.w)
                              : make_float2(v.x + v.z, v.y + v.w);
        st2(Pp, (size_t)jh * 256 + oct * 8 + r, res);
    }
}

// ===========================================================================
// FUSED PRODUCER DISPATCH: zeroF ∥ R ∥ A2 (mutually independent outputs).
// ===========================================================================
#define NA2_ (2 * C_ * A_ * 32)   // 3840 (a split out: short blocks interleave)
#define NR_  (25 * 512)           // 12800
#define NZ_  (OUTF_ / 256)        // 2560

__global__ __launch_bounds__(256)
void kernelU(const float* __restrict__ xr, const float* __restrict__ xi,
             const float* __restrict__ mr, const float* __restrict__ mi,
             const float* __restrict__ kr, const float* __restrict__ ki,
             h2* P, h2* Krev, float* outf) {
    __shared__ float2 twS[512];
    __shared__ float4 rows4[8][262];
    int blk = blockIdx.x;
    int t = threadIdx.x;
    if (blk < NA2_) {
        a2_body(blk, xr, xi, mr, mi, P, 0, t, twS, rows4);
    } else if (blk < NA2_ + NR_) {
        r_body(blk - NA2_, kr, ki, Krev, t);
    } else {
        outf[(size_t)(blk - NA2_ - NR_) * 256 + t] = 0.f;
    }
}

// ---- standalone wrappers (per-n schedule + fallback paths) ------------------
__global__ __launch_bounds__(256)
void zeroF(float* outf, int base) {
    outf[(size_t)base + blockIdx.x * 256 + threadIdx.x] = 0.f;
}

__global__ __launch_bounds__(256)
void kernelR(const float* __restrict__ kr, const float* __restrict__ ki,
             h2* Krev) {
    r_body(blockIdx.x, kr, ki, Krev, threadIdx.x);
}

__global__ __launch_bounds__(256)
void kernelA2(const float* __restrict__ xr, const float* __restrict__ xi,
              const float* __restrict__ mr, const float* __restrict__ mi,
              h2* P, int n0, int nspan) {
    (void)nspan;
    __shared__ float2 twS[512];
    __shared__ float4 rows4[8][262];
    a2_body(blockIdx.x, xr, xi, mr, mi, P, n0, threadIdx.x, twS, rows4);
}

// B2: 320 thr. Wave w owns array a=w (load, fwd FFT) AND output b=w (mix,
// inv FFT, store). NEW mix: each wave computes its own G[b=wv] over all 256
// f4-cols (4/lane) -> all 5 waves active (was t<256: wave 4 idle), K-load
// chains pipeline per-wave. In-place safe: all Fa reads precede the single
// syncthreads; wave wv's writes to Fa4[wv] are only read by wave wv (inv FFT).
// grid 8 XCD chunks x (64 jh x 12 c x nspan).
__global__ __launch_bounds__(320)
void kernelB2(const h2* __restrict__ Krev, h2* P, int nspan) {
    int blk = blockIdx.x;
    int xcd = blk & 7;
    int idx = blk >> 3;
    int cn  = 12 * nspan;
    int jh  = xcd * 64 + idx / cn;
    int rem = idx % cn;
    int c   = rem % 12;
    int nl  = rem / 12;
    int htrue = __brev((unsigned)jh) >> 23;
    int t = threadIdx.x;
    __shared__ float2 twS[512];
    __shared__ float4 Fa4[5][256];
    build_twS(twS, t);
    const float4* tw4 = (const float4*)twS;
    int wv = t >> 6, ln = t & 63;
    size_t pbase = (size_t)((nl * 12 + c) * 5) * IMGC_ + (size_t)jh * 256;

    // wave w loads array a=w (centered pad in w-dim; zeros never written)
    float2* Ff2 = (float2*)&Fa4[wv][0];
    const h2* Pa = P + pbase + (size_t)wv * IMGC_;
    #pragma unroll
    for (int k = 0; k < 4; k++) {
        int e = ln + 64 * k;
        float2 v = ld2(Pa, e);
        int ec = e + 128;
        Ff2[2 * PHI(ec >> 1) + (ec & 1)] = v;
    }
    __builtin_amdgcn_wave_barrier();

    float4* D = &Fa4[wv][0];
    fwd_quad0(D, tw4, ln);         __builtin_amdgcn_wave_barrier();
    fwd_quad(D, tw4, ln, 16, 192); __builtin_amdgcn_wave_barrier();
    fwd_quad(D, tw4, ln, 4, 240);  __builtin_amdgcn_wave_barrier();
    fwd_quad(D, tw4, ln, 1, 252);
    __syncthreads();   // all 5 arrays' forward FFTs done

    // mix: wave wv computes G[b=wv] at cols ln+64k, k=0..3 (coalesced K reads)
    const h2x2* Kp = reinterpret_cast<const h2x2*>(Krev);
    float4 acc[4];
    #pragma unroll
    for (int k = 0; k < 4; k++) {
        int col = ln + 64 * k;
        float2 a0 = make_float2(0.f, 0.f);
        float2 a1 = make_float2(0.f, 0.f);
        #pragma unroll
        for (int a = 0; a < 5; a++) {
            // fused fwd mm=1 on read: f0 = e0+e1, f1 = e0-e1
            float4 x = Fa4[a][PHI(col)];
            float2 f0 = make_float2(x.x + x.z, x.y + x.w);
            float2 f1 = make_float2(x.x - x.z, x.y - x.w);
            h2x2 kv = Kp[((size_t)(wv * 5 + a) * G_ + htrue) * 256 + col];
            float k0x = (float)kv.x0, k0y = (float)kv.y0;
            float k1x = (float)kv.x1, k1y = (float)kv.y1;
            a0.x += k0x * f0.x - k0y * f0.y;
            a0.y += k0x * f0.y + k0y * f0.x;
            a1.x += k1x * f1.x - k1y * f1.y;
            a1.y += k1x * f1.y + k1y * f1.x;
        }
        // fused inv mm=1 on write: (a0+a1, a0-a1)
        acc[k] = make_float4(a0.x + a1.x, a0.y + a1.y, a0.x - a1.x, a0.y - a1.y);
    }
    __syncthreads();   // every thread done READING all Fa4 arrays
    #pragma unroll
    for (int k = 0; k < 4; k++)
        Fa4[wv][PHI(ln + 64 * k)] = acc[k];
    __builtin_amdgcn_wave_barrier();   // own-wave writes visible for inv FFT

    inv_quad(D, tw4, ln, 1, 254, 252);  __builtin_amdgcn_wave_barrier();
    inv_quad(D, tw4, ln, 4, 248, 240);  __builtin_amdgcn_wave_barrier();
    inv_quad(D, tw4, ln, 16, 224, 192); __builtin_amdgcn_wave_barrier();
    inv_quad_crop(D, tw4, ln);          // only crop window written
    __builtin_amdgcn_wave_barrier();

    // wave w stores b=w (crop w-dim)
    h2* Pb = P + pbase + (size_t)wv * IMGC_;
    #pragma unroll
    for (int k = 0; k < 4; k++) {
        int e = ln + 64 * k;
        int ec = e + 128;
        float2 v = Ff2[2 * PHI(ec >> 1) + (ec & 1)];
        st2(Pb, e, v);
    }
}

// C2: block = (nl,b,oct,cg); loops 3 c's of group cg, accumulating
// Re(conj(mps)*IFFT_h(P)) in registers; 4 atomics/elem. grid(nspan*5*32*NCG_).
__global__ __launch_bounds__(256)
void kernelC2(const float* __restrict__ mr, const float* __restrict__ mi,
              const h2* __restrict__ P, float* outf, int n0, int nspan) {
    int blk = blockIdx.x;
    int oct = blk & 31;
    int b   = (blk >> 5) % 5;
    int rest = blk / 160;
    int cg = rest % NCG_;
    int nl = rest / NCG_;
    int n  = n0 + nl;
    int t = threadIdx.x;
    __shared__ float2 twS[512];
    __shared__ float4 rows4[8][262];
    build_twS(twS, t);
    const float4* tw4 = (const float4*)twS;

    int r = t & 7;
    int wc = oct * 8 + r;
    int wv = t >> 6, ln = t & 63;
    float4* d0 = &rows4[2 * wv][0];
    float4* d1 = &rows4[2 * wv + 1][0];
    const float2* rowf2 = (const float2*)&rows4[r][0];

    float acc[8];
    #pragma unroll
    for (int k = 0; k < 8; k++) acc[k] = 0.f;

    for (int ci = 0; ci < 3; ci++) {
        int c = cg * 3 + ci;
        const h2* Pb = P + (size_t)((nl * 12 + c) * 5 + b) * IMGC_;
        #pragma unroll
        for (int k = 0; k < 8; k++) {
            int jh0 = k * 64 + (t >> 3) * 2;
            float2 p0 = ld2(Pb, (size_t)jh0 * 256 + wc);
            float2 p1 = ld2(Pb, (size_t)(jh0 + 1) * 256 + wc);
            rows4[r][PHI(jh0 >> 1)] =
                make_float4(p0.x + p1.x, p0.y + p1.y, p0.x - p1.x, p0.y - p1.y);
        }
        __syncthreads();

        inv_quad(d0, tw4, ln, 1, 254, 252);  inv_quad(d1, tw4, ln, 1, 254, 252);
        __builtin_amdgcn_wave_barrier();
        inv_quad(d0, tw4, ln, 4, 248, 240);  inv_quad(d1, tw4, ln, 4, 248, 240);
        __builtin_amdgcn_wave_barrier();
        inv_quad(d0, tw4, ln, 16, 224, 192); inv_quad(d1, tw4, ln, 16, 224, 192);
        __builtin_amdgcn_wave_barrier();
        inv_quad_crop(d0, tw4, ln);          inv_quad_crop(d1, tw4, ln);
        __syncthreads();

        #pragma unroll
        for (int k = 0; k < 8; k++) {
            int hh = (t >> 3) + 32 * k;
            int e = hh + 128;
            float2 v = rowf2[2 * PHI(e >> 1) + (e & 1)];
            size_t mo = (((size_t)c) * H_ + hh) * H_ + wc;
            acc[k] += mr[mo] * v.x + mi[mo] * v.y;
        }
        __syncthreads();   // readout done before next c's load writes
    }

    #pragma unroll
    for (int k = 0; k < 8; k++) {
        int hh = (t >> 3) + 32 * k;
        size_t idx = (((size_t)n * A_ + b) * H_ + hh) * H_ + wc;
        unsafeAtomicAdd(&outf[idx], acc[k] * SCALE_);
    }
}

// ===========================================================================
// FALLBACK PATH (used when ws_size < 57.7 MB)
// ===========================================================================

__global__ __launch_bounds__(256)
void kernelA(const float* __restrict__ xr, const float* __restrict__ xi,
             const float* __restrict__ mr, const float* __restrict__ mi,
             h2* X1, int n, int c, int a) {
    int oct = blockIdx.x;
    int t = threadIdx.x;
    __shared__ float2 twS[512];
    __shared__ float2 rows[8][516];
    build_twS(twS, t);

    int r = t & 7;
    int wc = oct * 8 + r;
    #pragma unroll
    for (int k = 0; k < 8; k++) {
        int h = (t >> 3) + 32 * k;
        size_t xo = (((size_t)n * A_ + a) * H_ + h) * H_ + wc;
        size_t mo = (((size_t)c) * H_ + h) * H_ + wc;
        float xr_ = xr[xo], xi_ = xi[xo];
        float mr_ = mr[mo], mi_ = mi[mo];
        rows[r][h + 128] = make_float2(xr_ * mr_ - xi_ * mi_,
                                       xr_ * mi_ + xi_ * mr_);
        rows[r][(h < 128) ? h : (h + 256)] = make_float2(0.f, 0.f);
    }
    __syncthreads();
    for (int rr = 0; rr < 8; rr++) fft512_dif(&rows[rr][0], twS, t);

    #pragma unroll
    for (int k = 0; k < 16; k++) {
        int jh = k * 32 + (t >> 3);
        st2(X1, (size_t)jh * 256 + oct * 8 + (t & 7), rows[t & 7][jh]);
    }
}

__global__ __launch_bounds__(256)
void kernelB(const float* __restrict__ kr, const float* __restrict__ ki,
             const h2* X1, h2* X2, int b, int a) {
    int jh = blockIdx.x;
    int htrue = __brev((unsigned)jh) >> 23;
    int t = threadIdx.x;
    __shared__ float2 twS[512];
    __shared__ float2 F[512];
    __shared__ float2 g[512];
    build_twS(twS, t);

    float2 v = ld2(X1, (size_t)jh * 256 + t);
    F[t + 128] = v;
    F[(t < 128) ? t : (t + 256)] = make_float2(0.f, 0.f);
    __syncthreads();
    fft512_dif(F, twS, t);

    #pragma unroll
    for (int half = 0; half < 2; half++) {
        int jw = t + half * 256;
        int wtrue = __brev((unsigned)jw) >> 23;
        size_t kidx = (((size_t)(b * A_ + a)) * G_ + htrue) * G_ + wtrue;
        g[jw] = cmul(make_float2(kr[kidx], ki[kidx]), F[jw]);
    }
    ifft512_dit(g, twS, t);

    float2 res = g[t + 128];
    size_t o = (size_t)jh * 256 + t;
    if (a == 0) st2(X2, o, res);
    else {
        float2 cur = ld2(X2, o);
        st2(X2, o, make_float2(cur.x + res.x, cur.y + res.y));
    }
}

__global__ __launch_bounds__(256)
void kernelC(const float* __restrict__ mr, const float* __restrict__ mi,
             const h2* X2, float* outf, int n, int c, int b) {
    int oct = blockIdx.x;
    int t = threadIdx.x;
    __shared__ float2 twS[512];
    __shared__ float2 rows[8][516];
    build_twS(twS, t);

    #pragma unroll
    for (int k = 0; k < 16; k++) {
        int jh = k * 32 + (t >> 3);
        rows[t & 7][jh] = ld2(X2, (size_t)jh * 256 + oct * 8 + (t & 7));
    }
    for (int rr = 0; rr < 8; rr++) ifft512_dit(&rows[rr][0], twS, t);

    int r = t & 7;
    int wc = oct * 8 + r;
    #pragma unroll
    for (int k = 0; k < 8; k++) {
        int hh = (t >> 3) + 32 * k;
        float2 v = rows[r][hh + 128];
        size_t mo = (((size_t)c) * H_ + hh) * H_ + wc;
        float m_r = mr[mo], m_i = mi[mo];
        float re = (m_r * v.x + m_i * v.y) * SCALE_;
        size_t idx = (((size_t)n * A_ + b) * H_ + hh) * H_ + wc;
        outf[idx] += re;
    }
}

// ===========================================================================
extern "C" void kernel_launch(void* const* d_in, const int* in_sizes, int n_in,
                              void* d_out, int out_size, void* d_ws, size_t ws_size,
                              hipStream_t stream) {
    const float* xr = (const float*)d_in[0];
    const float* xi = (const float*)d_in[1];
    const float* mr = (const float*)d_in[2];
    const float* mi = (const float*)d_in[3];
    const float* kr = (const float*)d_in[4];
    const float* ki = (const float*)d_in[5];
    float* outf = (float*)d_out;
    (void)in_sizes; (void)n_in; (void)out_size;

    const size_t KREV_BYTES = 25ull * G_ * G_ * sizeof(h2);    // 26,214,400
    const size_t PLANES1    = 60ull * IMGC_ * sizeof(h2);      // 31,457,280
    const size_t PLANES2    = 120ull * IMGC_ * sizeof(h2);     // 62,914,560

    if (d_ws != nullptr && ws_size >= PLANES2 + KREV_BYTES) {
        // ---- fully fused: 3 dispatches (U = zeroF ∥ R ∥ A2; B2 320-thr)
        h2* P    = (h2*)d_ws;
        h2* Krev = (h2*)((char*)d_ws + PLANES2);
        kernelU<<<NA2_ + NR_ + NZ_, 256, 0, stream>>>(xr, xi, mr, mi, kr, ki,
                                                      P, Krev, outf);
        kernelB2<<<2 * C_ * 512, 320, 0, stream>>>(Krev, P, 2);
        kernelC2<<<2 * A_ * 32 * NCG_, 256, 0, stream>>>(mr, mi, P, outf, 0, 2);
        return;
    }

    if (d_ws != nullptr && ws_size >= PLANES1 + KREV_BYTES) {
        // ---- per-n schedule
        h2* P    = (h2*)d_ws;
        h2* Krev = (h2*)((char*)d_ws + PLANES1);
        zeroF<<<OUTF_ / 256, 256, 0, stream>>>(outf, 0);
        kernelR<<<25 * 512, 256, 0, stream>>>(kr, ki, Krev);
        for (int n = 0; n < N_; n++) {
            kernelA2<<<C_ * A_ * 32, 256, 0, stream>>>(xr, xi, mr, mi, P, n, 1);
            kernelB2<<<C_ * 512, 320, 0, stream>>>(Krev, P, 1);
            kernelC2<<<A_ * 32 * NCG_, 256, 0, stream>>>(mr, mi, P, outf, n, 1);
        }
        return;
    }

    // ---- fallback ----
    zeroF<<<HALFF_ / 256, 256, 0, stream>>>(outf, 0);
    {
        h2* X1 = (h2*)(outf + HALFF_);
        h2* X2 = (h2*)(outf + HALFF_ + IMGC_);
        for (int c = 0; c < C_; c++)
            for (int b = 0; b < A_; b++) {
                for (int a = 0; a < A_; a++) {
                    kernelA<<<32, 256, 0, stream>>>(xr, xi, mr, mi, X1, 0, c, a);
                    kernelB<<<512, 256, 0, stream>>>(kr, ki, X1, X2, b, a);
                }
                kernelC<<<32, 256, 0, stream>>>(mr, mi, X2, outf, 0, c, b);
            }
    }

    zeroF<<<HALFF_ / 256, 256, 0, stream>>>(outf, HALFF_);
    {
        h2* X1 = (h2*)d_in[0];
        h2* X2 = (h2*)d_in[1];
        for (int c = 0; c < C_; c++)
            for (int b = 0; b < A_; b++) {
                for (int a = 0; a < A_; a++) {
                    kernelA<<<32, 256, 0, stream>>>(xr, xi, mr, mi, X1, 1, c, a);
                    kernelB<<<512, 256, 0, stream>>>(kr, ki, X1, X2, b, a);
                }
                kernelC<<<32, 256, 0, stream>>>(mr, mi, X2, outf, 1, c, b);
            }
    }
}

// Round 15
// 387.678 us; speedup vs baseline: 1.3998x; 1.3998x over previous
//
#include <hip/hip_runtime.h>
#include <math.h>

#define N_ 2
#define A_ 5
#define C_ 12
#define H_ 256
#define G_ 512
// out = 4 * ifft_ortho(K * fft_ortho(...)) ==> 4/(512*512) on unnormalized FFTs
#define SCALE_ (4.0f / 262144.0f)
#define OUTF_ 655360       // out = fp32 REAL part, [2,5,256,256]
#define HALFF_ 327680      // per-n float count
#define IMGC_ 131072       // 512*256 complex: one spectral half-plane (h2 elems)
#define NCG_ 4             // C2 c-groups (3 c each)

// ---- fp16-pair scratch ------------------------------------------------------
struct __attribute__((aligned(4))) h2 { _Float16 x, y; };
struct __attribute__((aligned(8))) h2x2 { _Float16 x0, y0, x1, y1; };
__device__ __forceinline__ float2 ld2(const h2* p, size_t i) {
    h2 v = p[i]; return make_float2((float)v.x, (float)v.y);
}
__device__ __forceinline__ void st2(h2* p, size_t i, float2 v) {
    float x = fminf(fmaxf(v.x, -60000.f), 60000.f);   // never store inf
    float y = fminf(fmaxf(v.y, -60000.f), 60000.f);
    h2 o; o.x = (_Float16)x; o.y = (_Float16)y; p[i] = o;
}

__device__ __forceinline__ float2 cmul(float2 a, float2 b) {
    return make_float2(a.x * b.x - a.y * b.y, a.x * b.y + a.y * b.x);
}

// ---- float4 = two adjacent complexes helpers --------------------------------
__device__ __forceinline__ float4 qadd(float4 a, float4 b) {
    return make_float4(a.x + b.x, a.y + b.y, a.z + b.z, a.w + b.w);
}
__device__ __forceinline__ float4 qsub(float4 a, float4 b) {
    return make_float4(a.x - b.x, a.y - b.y, a.z - b.z, a.w - b.w);
}
__device__ __forceinline__ float4 qmul(float4 a, float4 w) {   // per-complex a*w
    return make_float4(a.x * w.x - a.y * w.y, a.x * w.y + a.y * w.x,
                       a.z * w.z - a.w * w.w, a.z * w.w + a.w * w.z);
}
__device__ __forceinline__ float4 qmulc(float4 a, float4 w) {  // per-complex a*conj(w)
    return make_float4(a.x * w.x + a.y * w.y, a.y * w.x - a.x * w.y,
                       a.z * w.z + a.w * w.w, a.w * w.z - a.z * w.w);
}
// f4-index bank swizzle: bijective within 8-blocks, kills stride-4/16 conflicts
__device__ __forceinline__ int PHI(int i) { return i ^ ((i >> 3) & 7); }

// Per-stage twiddle tables, float2 twS[512]:
//   stage half-size m occupies f2 [off, off+m), off = 0,256,384,448,480,496,
//   504,508,510; entry j = w^(j*(256/m)), w = exp(-2pi i/512).
__device__ __forceinline__ void build_twS(float2* twS, int t) {
    if (t < 256) {
        float s, c;
        sincosf(-6.283185307179586f * (float)t * (1.0f / 512.0f), &s, &c);
        twS[t] = make_float2(c, s);
    }
    __syncthreads();
    int off = 256;
    #pragma unroll
    for (int sh = 1; sh <= 8; sh++) {
        int sz = 256 >> sh;
        if (t < sz) twS[off + t] = twS[t << sh];
        off += sz;
    }
    __syncthreads();
}

// ---- radix-4 f4-paired LDS quads (proven R5 form) ---------------------------
__device__ __forceinline__ void fwd_quad(float4* D, const float4* tw4,
                                         int bt, int M4, int offA4) {
    int jf = bt & (M4 - 1);
    int f0 = ((bt & ~(M4 - 1)) << 2) | jf;
    float4 x0 = D[PHI(f0)],          x1 = D[PHI(f0 + M4)];
    float4 x2 = D[PHI(f0 + 2 * M4)], x3 = D[PHI(f0 + 3 * M4)];
    float4 tA  = tw4[offA4 + jf];
    float4 tA2 = tw4[offA4 + M4 + jf];
    float4 tB  = tw4[offA4 + 2 * M4 + jf];
    float4 u0 = qadd(x0, x2), v0 = qmul(qsub(x0, x2), tA);
    float4 u1 = qadd(x1, x3), v1 = qmul(qsub(x1, x3), tA2);
    D[PHI(f0)]          = qadd(u0, u1);
    D[PHI(f0 + M4)]     = qmul(qsub(u0, u1), tB);
    D[PHI(f0 + 2 * M4)] = qadd(v0, v1);
    D[PHI(f0 + 3 * M4)] = qmul(qsub(v0, v1), tB);
}
// First fwd stage-pair (M4=64, offA4=0) with x0 = x3 = 0 (centered zero-pad:
// positions [0,128) and [384,512) are zero = f4 cols [0,64) and [192,256)).
// Outputs bit-identical to fwd_quad on zero-filled input.
__device__ __forceinline__ void fwd_quad0(float4* D, const float4* tw4, int bt) {
    int f0 = bt;   // jf = bt, M4 = 64
    float4 x1 = D[PHI(f0 + 64)];
    float4 x2 = D[PHI(f0 + 128)];
    float4 tA  = tw4[f0];
    float4 tA2 = tw4[64 + f0];
    float4 tB  = tw4[128 + f0];
    float4 zero = make_float4(0.f, 0.f, 0.f, 0.f);
    float4 v0 = qmul(qsub(zero, x2), tA);   // (x0 - x2)*tA with x0 = 0
    float4 v1 = qmul(x1, tA2);              // (x1 - x3)*tA2 with x3 = 0
    D[PHI(f0)]       = qadd(x2, x1);        // u0 + u1
    D[PHI(f0 + 64)]  = qmul(qsub(x2, x1), tB);
    D[PHI(f0 + 128)] = qadd(v0, v1);
    D[PHI(f0 + 192)] = qmul(qsub(v0, v1), tB);
}
__device__ __forceinline__ void inv_quad(float4* D, const float4* tw4,
                                         int bt, int M2, int offM4, int off2M4) {
    int jf = bt & (M2 - 1);
    int f0 = ((bt & ~(M2 - 1)) << 2) | jf;
    float4 x0 = D[PHI(f0)],          x1 = D[PHI(f0 + M2)];
    float4 x2 = D[PHI(f0 + 2 * M2)], x3 = D[PHI(f0 + 3 * M2)];
    float4 wA  = tw4[offM4 + jf];
    float4 wB0 = tw4[off2M4 + jf];
    float4 wB1 = tw4[off2M4 + M2 + jf];
    float4 t1 = qmulc(x1, wA), t3 = qmulc(x3, wA);
    float4 u0 = qadd(x0, t1), u1 = qsub(x0, t1);
    float4 u2 = qadd(x2, t3), u3 = qsub(x2, t3);
    float4 s2 = qmulc(u2, wB0), s3 = qmulc(u3, wB1);
    D[PHI(f0)]          = qadd(u0, s2);
    D[PHI(f0 + M2)]     = qadd(u1, s3);
    D[PHI(f0 + 2 * M2)] = qsub(u0, s2);
    D[PHI(f0 + 3 * M2)] = qsub(u1, s3);
}
// Last inv stage-pair (M2=64, offM4=128, off2M4=0) writing ONLY the crop
// window f4 [64,192) (= positions [128,384)). Retained values bit-identical.
__device__ __forceinline__ void inv_quad_crop(float4* D, const float4* tw4,
                                              int bt) {
    int f0 = bt;   // jf = bt, M2 = 64
    float4 x0 = D[PHI(f0)],       x1 = D[PHI(f0 + 64)];
    float4 x2 = D[PHI(f0 + 128)], x3 = D[PHI(f0 + 192)];
    float4 wA  = tw4[128 + f0];
    float4 wB0 = tw4[f0];
    float4 wB1 = tw4[64 + f0];
    float4 t1 = qmulc(x1, wA), t3 = qmulc(x3, wA);
    float4 u0 = qadd(x0, t1), u1 = qsub(x0, t1);
    float4 u2 = qadd(x2, t3), u3 = qsub(x2, t3);
    float4 s2 = qmulc(u2, wB0), s3 = qmulc(u3, wB1);
    D[PHI(f0 + 64)]  = qadd(u1, s3);
    D[PHI(f0 + 128)] = qsub(u0, s2);
}

// ---- legacy single-array radix-2 FFTs (fallback path only) ------------------
__device__ void fft512_dif(float2* d, const float2* twS, int t) {
    int off = 0;
    #pragma unroll
    for (int m = 256; m >= 1; m >>= 1) {
        if (m >= 64) __syncthreads();
        else __builtin_amdgcn_wave_barrier();
        int j = t & (m - 1);
        int p = ((t & ~(m - 1)) << 1) | j;
        int q = p + m;
        float2 a = d[p], b = d[q];
        d[p] = make_float2(a.x + b.x, a.y + b.y);
        float2 s = make_float2(a.x - b.x, a.y - b.y);
        d[q] = cmul(s, twS[off + j]);
        off += m;
    }
    __syncthreads();
}
__device__ void ifft512_dit(float2* d, const float2* twS, int t) {
    int off = 510;
    #pragma unroll
    for (int m = 1; m <= 256; m <<= 1) {
        if (m == 1 || m >= 128) __syncthreads();
        else __builtin_amdgcn_wave_barrier();
        int j = t & (m - 1);
        int p = ((t & ~(m - 1)) << 1) | j;
        int q = p + m;
        float2 w = twS[off + j];
        w.y = -w.y;
        float2 b = cmul(d[q], w);
        float2 a = d[p];
        d[p] = make_float2(a.x + b.x, a.y + b.y);
        d[q] = make_float2(a.x - b.x, a.y - b.y);
        off -= (m << 1);
    }
    __syncthreads();
}

// ---- zero a float range of out ---------------------------------------------
__global__ __launch_bounds__(256)
void zeroF(float* outf, int base) {
    outf[(size_t)base + blockIdx.x * 256 + threadIdx.x] = 0.f;
}

// ===========================================================================
// FAST PATH. P holds nspan*60 half-planes [nl][c][a]; Krev is the
// bit-reversed-w fp16 kernel copy.
// ===========================================================================

// R: Krev[p][h][jw] = K[p][h][brev9(jw)], p = b*5+a. grid(25*512).
__global__ __launch_bounds__(256)
void kernelR(const float* __restrict__ kr, const float* __restrict__ ki,
             h2* Krev) {
    int p = blockIdx.x >> 9;
    int h = blockIdx.x & 511;
    int t = threadIdx.x;
    size_t base = ((size_t)p * G_ + h) * G_;
    int j0 = __brev((unsigned)t) >> 23;
    int j1 = __brev((unsigned)(t + 256)) >> 23;
    st2(Krev, base + t,       make_float2(kr[base + j0], ki[base + j0]));
    st2(Krev, base + t + 256, make_float2(kr[base + j1], ki[base + j1]));
}

// A2: block = (nl,c,oct); loops a=0..4 with mps columns hoisted in registers.
// Per a: x*mps, pad h (implicit: zeros never written, fwd_quad0 skips them),
// fwd FFT_h, transposed store to P[nl,c,a]. grid(nspan*12*32), 256 thr.
__global__ __launch_bounds__(256)
void kernelA2(const float* __restrict__ xr, const float* __restrict__ xi,
              const float* __restrict__ mr, const float* __restrict__ mi,
              h2* P, int n0, int nspan) {
    int blk = blockIdx.x;
    int oct = blk & 31;
    int rest = blk >> 5;
    int c  = rest % 12;
    int nl = rest / 12;
    int n  = n0 + nl;
    int t = threadIdx.x;
    __shared__ float2 twS[512];
    __shared__ float4 rows4[8][262];
    build_twS(twS, t);
    const float4* tw4 = (const float4*)twS;

    int r = t & 7;
    int wc = oct * 8 + r;
    // hoist mps columns (reused across all 5 a)
    float mR[8], mI[8];
    #pragma unroll
    for (int k = 0; k < 8; k++) {
        int h = (t >> 3) + 32 * k;
        size_t mo = ((size_t)c * H_ + h) * H_ + wc;
        mR[k] = mr[mo]; mI[k] = mi[mo];
    }
    float2* rowf2 = (float2*)&rows4[r][0];
    int wv = t >> 6, ln = t & 63;
    float4* d0 = &rows4[2 * wv][0];
    float4* d1 = &rows4[2 * wv + 1][0];

    for (int a = 0; a < 5; a++) {
        #pragma unroll
        for (int k = 0; k < 8; k++) {
            int h = (t >> 3) + 32 * k;
            size_t xo = (((size_t)n * A_ + a) * H_ + h) * H_ + wc;
            float xr_ = xr[xo], xi_ = xi[xo];
            int e = h + 128;
            rowf2[2 * PHI(e >> 1) + (e & 1)] =
                make_float2(xr_ * mR[k] - xi_ * mI[k],
                            xr_ * mI[k] + xi_ * mR[k]);
            // pad zeros not written: fwd_quad0 never reads them
        }
        __syncthreads();

        fwd_quad0(d0, tw4, ln);         fwd_quad0(d1, tw4, ln);
        __builtin_amdgcn_wave_barrier();
        fwd_quad(d0, tw4, ln, 16, 192); fwd_quad(d1, tw4, ln, 16, 192);
        __builtin_amdgcn_wave_barrier();
        fwd_quad(d0, tw4, ln, 4, 240);  fwd_quad(d1, tw4, ln, 4, 240);
        __builtin_amdgcn_wave_barrier();
        fwd_quad(d0, tw4, ln, 1, 252);  fwd_quad(d1, tw4, ln, 1, 252);
        __syncthreads();

        h2* Pp = P + (size_t)((nl * 12 + c) * 5 + a) * IMGC_;
        #pragma unroll
        for (int k = 0; k < 16; k++) {
            int jh = k * 32 + (t >> 3);
            float4 v = rows4[r][PHI(jh >> 1)];
            float2 res = (jh & 1) ? make_float2(v.x - v.z, v.y - v.w)
                                  : make_float2(v.x + v.z, v.y + v.w);
            st2(Pp, (size_t)jh * 256 + oct * 8 + r, res);
        }
        __syncthreads();   // store reads done before next a's pad writes
    }
}

// B2: 320 thr, wave w owns array a=w (load, fwd FFT) and b=w (inv FFT, store);
// mix is pointwise per f4-column -> in-place, 4 syncthreads total.
// grid 8 XCD chunks x (64 jh x 12 c x nspan).
__global__ __launch_bounds__(320)
void kernelB2(const h2* __restrict__ Krev, h2* P, int nspan) {
    int blk = blockIdx.x;
    int xcd = blk & 7;
    int idx = blk >> 3;
    int cn  = 12 * nspan;
    int jh  = xcd * 64 + idx / cn;
    int rem = idx % cn;
    int c   = rem % 12;
    int nl  = rem / 12;
    int htrue = __brev((unsigned)jh) >> 23;
    int t = threadIdx.x;
    __shared__ float2 twS[512];
    __shared__ float4 Fa4[5][256];
    build_twS(twS, t);
    const float4* tw4 = (const float4*)twS;
    int wv = t >> 6, ln = t & 63;
    size_t pbase = (size_t)((nl * 12 + c) * 5) * IMGC_ + (size_t)jh * 256;

    // wave w loads array a=w (centered pad in w-dim; zeros never written)
    float2* Ff2 = (float2*)&Fa4[wv][0];
    const h2* Pa = P + pbase + (size_t)wv * IMGC_;
    #pragma unroll
    for (int k = 0; k < 4; k++) {
        int e = ln + 64 * k;
        float2 v = ld2(Pa, e);
        int ec = e + 128;
        Ff2[2 * PHI(ec >> 1) + (ec & 1)] = v;
    }
    __builtin_amdgcn_wave_barrier();

    float4* D = &Fa4[wv][0];
    fwd_quad0(D, tw4, ln);         __builtin_amdgcn_wave_barrier();
    fwd_quad(D, tw4, ln, 16, 192); __builtin_amdgcn_wave_barrier();
    fwd_quad(D, tw4, ln, 4, 240);  __builtin_amdgcn_wave_barrier();
    fwd_quad(D, tw4, ln, 1, 252);
    __syncthreads();   // all 5 arrays' forward FFTs done

    if (t < 256) {
        // fused fwd mm=1 on read: F[2t] = e0+e1, F[2t+1] = e0-e1
        float2 f0[5], f1[5];
        #pragma unroll
        for (int a = 0; a < 5; a++) {
            float4 x = Fa4[a][PHI(t)];
            f0[a] = make_float2(x.x + x.z, x.y + x.w);
            f1[a] = make_float2(x.x - x.z, x.y - x.w);
        }
        const h2x2* Kp = reinterpret_cast<const h2x2*>(Krev);
        #pragma unroll
        for (int b = 0; b < 5; b++) {
            float2 a0 = make_float2(0.f, 0.f);
            float2 a1 = make_float2(0.f, 0.f);
            #pragma unroll
            for (int a = 0; a < 5; a++) {
                h2x2 kv = Kp[((size_t)(b * 5 + a) * G_ + htrue) * 256 + t];
                float k0x = (float)kv.x0, k0y = (float)kv.y0;
                float k1x = (float)kv.x1, k1y = (float)kv.y1;
                a0.x += k0x * f0[a].x - k0y * f0[a].y;
                a0.y += k0x * f0[a].y + k0y * f0[a].x;
                a1.x += k1x * f1[a].x - k1y * f1[a].y;
                a1.y += k1x * f1[a].y + k1y * f1[a].x;
            }
            // fused inv mm=1 on write: (a0+a1, a0-a1) in place over Fa
            Fa4[b][PHI(t)] =
                make_float4(a0.x + a1.x, a0.y + a1.y, a0.x - a1.x, a0.y - a1.y);
        }
    }
    __syncthreads();   // mix writes visible

    inv_quad(D, tw4, ln, 1, 254, 252);  __builtin_amdgcn_wave_barrier();
    inv_quad(D, tw4, ln, 4, 248, 240);  __builtin_amdgcn_wave_barrier();
    inv_quad(D, tw4, ln, 16, 224, 192); __builtin_amdgcn_wave_barrier();
    inv_quad_crop(D, tw4, ln);          // only crop window written
    __builtin_amdgcn_wave_barrier();

    // wave w stores b=w (crop w-dim)
    h2* Pb = P + pbase + (size_t)wv * IMGC_;
    #pragma unroll
    for (int k = 0; k < 4; k++) {
        int e = ln + 64 * k;
        int ec = e + 128;
        float2 v = Ff2[2 * PHI(ec >> 1) + (ec & 1)];
        st2(Pb, e, v);
    }
}

// C2: block = (nl,b,oct,cg); loops 3 c's of group cg, accumulating
// Re(conj(mps)*IFFT_h(P)) in registers; 4 atomics/elem instead of 12.
// grid(nspan*5*32*NCG_), 256 thr.
__global__ __launch_bounds__(256)
void kernelC2(const float* __restrict__ mr, const float* __restrict__ mi,
              const h2* __restrict__ P, float* outf, int n0, int nspan) {
    int blk = blockIdx.x;
    int oct = blk & 31;
    int b   = (blk >> 5) % 5;
    int rest = blk / 160;
    int cg = rest % NCG_;
    int nl = rest / NCG_;
    int n  = n0 + nl;
    int t = threadIdx.x;
    __shared__ float2 twS[512];
    __shared__ float4 rows4[8][262];
    build_twS(twS, t);
    const float4* tw4 = (const float4*)twS;

    int r = t & 7;
    int wc = oct * 8 + r;
    int wv = t >> 6, ln = t & 63;
    float4* d0 = &rows4[2 * wv][0];
    float4* d1 = &rows4[2 * wv + 1][0];
    const float2* rowf2 = (const float2*)&rows4[r][0];

    float acc[8];
    #pragma unroll
    for (int k = 0; k < 8; k++) acc[k] = 0.f;

    for (int ci = 0; ci < 3; ci++) {
        int c = cg * 3 + ci;
        const h2* Pb = P + (size_t)((nl * 12 + c) * 5 + b) * IMGC_;
        #pragma unroll
        for (int k = 0; k < 8; k++) {
            int jh0 = k * 64 + (t >> 3) * 2;
            float2 p0 = ld2(Pb, (size_t)jh0 * 256 + wc);
            float2 p1 = ld2(Pb, (size_t)(jh0 + 1) * 256 + wc);
            rows4[r][PHI(jh0 >> 1)] =
                make_float4(p0.x + p1.x, p0.y + p1.y, p0.x - p1.x, p0.y - p1.y);
        }
        __syncthreads();

        inv_quad(d0, tw4, ln, 1, 254, 252);  inv_quad(d1, tw4, ln, 1, 254, 252);
        __builtin_amdgcn_wave_barrier();
        inv_quad(d0, tw4, ln, 4, 248, 240);  inv_quad(d1, tw4, ln, 4, 248, 240);
        __builtin_amdgcn_wave_barrier();
        inv_quad(d0, tw4, ln, 16, 224, 192); inv_quad(d1, tw4, ln, 16, 224, 192);
        __builtin_amdgcn_wave_barrier();
        inv_quad_crop(d0, tw4, ln);          inv_quad_crop(d1, tw4, ln);
        __syncthreads();

        #pragma unroll
        for (int k = 0; k < 8; k++) {
            int hh = (t >> 3) + 32 * k;
            int e = hh + 128;
            float2 v = rowf2[2 * PHI(e >> 1) + (e & 1)];
            size_t mo = (((size_t)c) * H_ + hh) * H_ + wc;
            acc[k] += mr[mo] * v.x + mi[mo] * v.y;
        }
        __syncthreads();   // readout done before next c's load writes
    }

    #pragma unroll
    for (int k = 0; k < 8; k++) {
        int hh = (t >> 3) + 32 * k;
        size_t idx = (((size_t)n * A_ + b) * H_ + hh) * H_ + wc;
        unsafeAtomicAdd(&outf[idx], acc[k] * SCALE_);
    }
}

// ===========================================================================
// FALLBACK PATH (used when ws_size < 57.7 MB)
// ===========================================================================

__global__ __launch_bounds__(256)
void kernelA(const float* __restrict__ xr, const float* __restrict__ xi,
             const float* __restrict__ mr, const float* __restrict__ mi,
             h2* X1, int n, int c, int a) {
    int oct = blockIdx.x;
    int t = threadIdx.x;
    __shared__ float2 twS[512];
    __shared__ float2 rows[8][516];
    build_twS(twS, t);

    int r = t & 7;
    int wc = oct * 8 + r;
    #pragma unroll
    for (int k = 0; k < 8; k++) {
        int h = (t >> 3) + 32 * k;
        size_t xo = (((size_t)n * A_ + a) * H_ + h) * H_ + wc;
        size_t mo = (((size_t)c) * H_ + h) * H_ + wc;
        float xr_ = xr[xo], xi_ = xi[xo];
        float mr_ = mr[mo], mi_ = mi[mo];
        rows[r][h + 128] = make_float2(xr_ * mr_ - xi_ * mi_,
                                       xr_ * mi_ + xi_ * mr_);
        rows[r][(h < 128) ? h : (h + 256)] = make_float2(0.f, 0.f);
    }
    __syncthreads();
    for (int rr = 0; rr < 8; rr++) fft512_dif(&rows[rr][0], twS, t);

    #pragma unroll
    for (int k = 0; k < 16; k++) {
        int jh = k * 32 + (t >> 3);
        st2(X1, (size_t)jh * 256 + oct * 8 + (t & 7), rows[t & 7][jh]);
    }
}

__global__ __launch_bounds__(256)
void kernelB(const float* __restrict__ kr, const float* __restrict__ ki,
             const h2* X1, h2* X2, int b, int a) {
    int jh = blockIdx.x;
    int htrue = __brev((unsigned)jh) >> 23;
    int t = threadIdx.x;
    __shared__ float2 twS[512];
    __shared__ float2 F[512];
    __shared__ float2 g[512];
    build_twS(twS, t);

    float2 v = ld2(X1, (size_t)jh * 256 + t);
    F[t + 128] = v;
    F[(t < 128) ? t : (t + 256)] = make_float2(0.f, 0.f);
    __syncthreads();
    fft512_dif(F, twS, t);

    #pragma unroll
    for (int half = 0; half < 2; half++) {
        int jw = t + half * 256;
        int wtrue = __brev((unsigned)jw) >> 23;
        size_t kidx = (((size_t)(b * A_ + a)) * G_ + htrue) * G_ + wtrue;
        g[jw] = cmul(make_float2(kr[kidx], ki[kidx]), F[jw]);
    }
    ifft512_dit(g, twS, t);

    float2 res = g[t + 128];
    size_t o = (size_t)jh * 256 + t;
    if (a == 0) st2(X2, o, res);
    else {
        float2 cur = ld2(X2, o);
        st2(X2, o, make_float2(cur.x + res.x, cur.y + res.y));
    }
}

__global__ __launch_bounds__(256)
void kernelC(const float* __restrict__ mr, const float* __restrict__ mi,
             const h2* X2, float* outf, int n, int c, int b) {
    int oct = blockIdx.x;
    int t = threadIdx.x;
    __shared__ float2 twS[512];
    __shared__ float2 rows[8][516];
    build_twS(twS, t);

    #pragma unroll
    for (int k = 0; k < 16; k++) {
        int jh = k * 32 + (t >> 3);
        rows[t & 7][jh] = ld2(X2, (size_t)jh * 256 + oct * 8 + (t & 7));
    }
    for (int rr = 0; rr < 8; rr++) ifft512_dit(&rows[rr][0], twS, t);

    int r = t & 7;
    int wc = oct * 8 + r;
    #pragma unroll
    for (int k = 0; k < 8; k++) {
        int hh = (t >> 3) + 32 * k;
        float2 v = rows[r][hh + 128];
        size_t mo = (((size_t)c) * H_ + hh) * H_ + wc;
        float m_r = mr[mo], m_i = mi[mo];
        float re = (m_r * v.x + m_i * v.y) * SCALE_;
        size_t idx = (((size_t)n * A_ + b) * H_ + hh) * H_ + wc;
        outf[idx] += re;
    }
}

// ===========================================================================
extern "C" void kernel_launch(void* const* d_in, const int* in_sizes, int n_in,
                              void* d_out, int out_size, void* d_ws, size_t ws_size,
                              hipStream_t stream) {
    const float* xr = (const float*)d_in[0];
    const float* xi = (const float*)d_in[1];
    const float* mr = (const float*)d_in[2];
    const float* mi = (const float*)d_in[3];
    const float* kr = (const float*)d_in[4];
    const float* ki = (const float*)d_in[5];
    float* outf = (float*)d_out;
    (void)in_sizes; (void)n_in; (void)out_size;

    const size_t KREV_BYTES = 25ull * G_ * G_ * sizeof(h2);    // 26,214,400
    const size_t PLANES1    = 60ull * IMGC_ * sizeof(h2);      // 31,457,280
    const size_t PLANES2    = 120ull * IMGC_ * sizeof(h2);     // 62,914,560

    if (d_ws != nullptr && ws_size >= PLANES2 + KREV_BYTES) {
        // ---- fully fused: both n in every dispatch (5 dispatches total)
        h2* P    = (h2*)d_ws;
        h2* Krev = (h2*)((char*)d_ws + PLANES2);
        zeroF<<<OUTF_ / 256, 256, 0, stream>>>(outf, 0);
        kernelR<<<25 * 512, 256, 0, stream>>>(kr, ki, Krev);
        kernelA2<<<2 * C_ * 32, 256, 0, stream>>>(xr, xi, mr, mi, P, 0, 2);
        kernelB2<<<2 * C_ * 512, 320, 0, stream>>>(Krev, P, 2);
        kernelC2<<<2 * A_ * 32 * NCG_, 256, 0, stream>>>(mr, mi, P, outf, 0, 2);
        return;
    }

    if (d_ws != nullptr && ws_size >= PLANES1 + KREV_BYTES) {
        // ---- per-n schedule
        h2* P    = (h2*)d_ws;
        h2* Krev = (h2*)((char*)d_ws + PLANES1);
        zeroF<<<OUTF_ / 256, 256, 0, stream>>>(outf, 0);
        kernelR<<<25 * 512, 256, 0, stream>>>(kr, ki, Krev);
        for (int n = 0; n < N_; n++) {
            kernelA2<<<C_ * 32, 256, 0, stream>>>(xr, xi, mr, mi, P, n, 1);
            kernelB2<<<C_ * 512, 320, 0, stream>>>(Krev, P, 1);
            kernelC2<<<A_ * 32 * NCG_, 256, 0, stream>>>(mr, mi, P, outf, n, 1);
        }
        return;
    }

    // ---- fallback ----
    zeroF<<<HALFF_ / 256, 256, 0, stream>>>(outf, 0);
    {
        h2* X1 = (h2*)(outf + HALFF_);
        h2* X2 = (h2*)(outf + HALFF_ + IMGC_);
        for (int c = 0; c < C_; c++)
            for (int b = 0; b < A_; b++) {
                for (int a = 0; a < A_; a++) {
                    kernelA<<<32, 256, 0, stream>>>(xr, xi, mr, mi, X1, 0, c, a);
                    kernelB<<<512, 256, 0, stream>>>(kr, ki, X1, X2, b, a);
                }
                kernelC<<<32, 256, 0, stream>>>(mr, mi, X2, outf, 0, c, b);
            }
    }

    zeroF<<<HALFF_ / 256, 256, 0, stream>>>(outf, HALFF_);
    {
        h2* X1 = (h2*)d_in[0];
        h2* X2 = (h2*)d_in[1];
        for (int c = 0; c < C_; c++)
            for (int b = 0; b < A_; b++) {
                for (int a = 0; a < A_; a++) {
                    kernelA<<<32, 256, 0, stream>>>(xr, xi, mr, mi, X1, 1, c, a);
                    kernelB<<<512, 256, 0, stream>>>(kr, ki, X1, X2, b, a);
                }
                kernelC<<<32, 256, 0, stream>>>(mr, mi, X2, outf, 1, c, b);
            }
    }
}

// Round 16
// 374.104 us; speedup vs baseline: 1.4506x; 1.0363x over previous
//
#include <hip/hip_runtime.h>
#include <math.h>

#define N_ 2
#define A_ 5
#define C_ 12
#define H_ 256
#define G_ 512
// out = 4 * ifft_ortho(K * fft_ortho(...)) ==> 4/(512*512) on unnormalized FFTs
#define SCALE_ (4.0f / 262144.0f)
#define OUTF_ 655360       // out = fp32 REAL part, [2,5,256,256]
#define HALFF_ 327680      // per-n float count
#define IMGC_ 131072       // 512*256 complex: one spectral half-plane (h2 elems)
#define NCG_ 4             // C2 c-groups (3 c each)

// ---- fp16-pair scratch ------------------------------------------------------
struct __attribute__((aligned(4))) h2 { _Float16 x, y; };
struct __attribute__((aligned(8))) h2x2 { _Float16 x0, y0, x1, y1; };
struct __attribute__((aligned(16))) h2x4 { _Float16 x0, y0, x1, y1, x2, y2, x3, y3; };
__device__ __forceinline__ float2 ld2(const h2* p, size_t i) {
    h2 v = p[i]; return make_float2((float)v.x, (float)v.y);
}
__device__ __forceinline__ void st2(h2* p, size_t i, float2 v) {
    float x = fminf(fmaxf(v.x, -60000.f), 60000.f);   // never store inf
    float y = fminf(fmaxf(v.y, -60000.f), 60000.f);
    h2 o; o.x = (_Float16)x; o.y = (_Float16)y; p[i] = o;
}

__device__ __forceinline__ float2 cmul(float2 a, float2 b) {
    return make_float2(a.x * b.x - a.y * b.y, a.x * b.y + a.y * b.x);
}

// ---- float4 = two adjacent complexes helpers --------------------------------
__device__ __forceinline__ float4 qadd(float4 a, float4 b) {
    return make_float4(a.x + b.x, a.y + b.y, a.z + b.z, a.w + b.w);
}
__device__ __forceinline__ float4 qsub(float4 a, float4 b) {
    return make_float4(a.x - b.x, a.y - b.y, a.z - b.z, a.w - b.w);
}
__device__ __forceinline__ float4 qmul(float4 a, float4 w) {   // per-complex a*w
    return make_float4(a.x * w.x - a.y * w.y, a.x * w.y + a.y * w.x,
                       a.z * w.z - a.w * w.w, a.z * w.w + a.w * w.z);
}
__device__ __forceinline__ float4 qmulc(float4 a, float4 w) {  // per-complex a*conj(w)
    return make_float4(a.x * w.x + a.y * w.y, a.y * w.x - a.x * w.y,
                       a.z * w.z + a.w * w.w, a.w * w.z - a.z * w.w);
}
// f4-index bank swizzle: bijective within 8-blocks, kills stride-4/16 conflicts
__device__ __forceinline__ int PHI(int i) { return i ^ ((i >> 3) & 7); }

// Per-stage twiddle tables, float2 twS[512]:
//   stage half-size m occupies f2 [off, off+m), off = 0,256,384,448,480,496,
//   504,508,510; entry j = w^(j*(256/m)), w = exp(-2pi i/512).
__device__ __forceinline__ void build_twS(float2* twS, int t) {
    if (t < 256) {
        float s, c;
        sincosf(-6.283185307179586f * (float)t * (1.0f / 512.0f), &s, &c);
        twS[t] = make_float2(c, s);
    }
    __syncthreads();
    int off = 256;
    #pragma unroll
    for (int sh = 1; sh <= 8; sh++) {
        int sz = 256 >> sh;
        if (t < sz) twS[off + t] = twS[t << sh];
        off += sz;
    }
    __syncthreads();
}

// ---- radix-4 f4-paired LDS quads (proven R5 form) ---------------------------
__device__ __forceinline__ void fwd_quad(float4* D, const float4* tw4,
                                         int bt, int M4, int offA4) {
    int jf = bt & (M4 - 1);
    int f0 = ((bt & ~(M4 - 1)) << 2) | jf;
    float4 x0 = D[PHI(f0)],          x1 = D[PHI(f0 + M4)];
    float4 x2 = D[PHI(f0 + 2 * M4)], x3 = D[PHI(f0 + 3 * M4)];
    float4 tA  = tw4[offA4 + jf];
    float4 tA2 = tw4[offA4 + M4 + jf];
    float4 tB  = tw4[offA4 + 2 * M4 + jf];
    float4 u0 = qadd(x0, x2), v0 = qmul(qsub(x0, x2), tA);
    float4 u1 = qadd(x1, x3), v1 = qmul(qsub(x1, x3), tA2);
    D[PHI(f0)]          = qadd(u0, u1);
    D[PHI(f0 + M4)]     = qmul(qsub(u0, u1), tB);
    D[PHI(f0 + 2 * M4)] = qadd(v0, v1);
    D[PHI(f0 + 3 * M4)] = qmul(qsub(v0, v1), tB);
}
// First fwd stage-pair (M4=64, offA4=0) with x0 = x3 = 0 (centered zero-pad:
// positions [0,128) and [384,512) are zero = f4 cols [0,64) and [192,256)).
// Outputs bit-identical to fwd_quad on zero-filled input.
__device__ __forceinline__ void fwd_quad0(float4* D, const float4* tw4, int bt) {
    int f0 = bt;   // jf = bt, M4 = 64
    float4 x1 = D[PHI(f0 + 64)];
    float4 x2 = D[PHI(f0 + 128)];
    float4 tA  = tw4[f0];
    float4 tA2 = tw4[64 + f0];
    float4 tB  = tw4[128 + f0];
    float4 zero = make_float4(0.f, 0.f, 0.f, 0.f);
    float4 v0 = qmul(qsub(zero, x2), tA);   // (x0 - x2)*tA with x0 = 0
    float4 v1 = qmul(x1, tA2);              // (x1 - x3)*tA2 with x3 = 0
    D[PHI(f0)]       = qadd(x2, x1);        // u0 + u1
    D[PHI(f0 + 64)]  = qmul(qsub(x2, x1), tB);
    D[PHI(f0 + 128)] = qadd(v0, v1);
    D[PHI(f0 + 192)] = qmul(qsub(v0, v1), tB);
}
__device__ __forceinline__ void inv_quad(float4* D, const float4* tw4,
                                         int bt, int M2, int offM4, int off2M4) {
    int jf = bt & (M2 - 1);
    int f0 = ((bt & ~(M2 - 1)) << 2) | jf;
    float4 x0 = D[PHI(f0)],          x1 = D[PHI(f0 + M2)];
    float4 x2 = D[PHI(f0 + 2 * M2)], x3 = D[PHI(f0 + 3 * M2)];
    float4 wA  = tw4[offM4 + jf];
    float4 wB0 = tw4[off2M4 + jf];
    float4 wB1 = tw4[off2M4 + M2 + jf];
    float4 t1 = qmulc(x1, wA), t3 = qmulc(x3, wA);
    float4 u0 = qadd(x0, t1), u1 = qsub(x0, t1);
    float4 u2 = qadd(x2, t3), u3 = qsub(x2, t3);
    float4 s2 = qmulc(u2, wB0), s3 = qmulc(u3, wB1);
    D[PHI(f0)]          = qadd(u0, s2);
    D[PHI(f0 + M2)]     = qadd(u1, s3);
    D[PHI(f0 + 2 * M2)] = qsub(u0, s2);
    D[PHI(f0 + 3 * M2)] = qsub(u1, s3);
}
// Last inv stage-pair (M2=64, offM4=128, off2M4=0) writing ONLY the crop
// window f4 [64,192) (= positions [128,384)). Retained values bit-identical.
__device__ __forceinline__ void inv_quad_crop(float4* D, const float4* tw4,
                                              int bt) {
    int f0 = bt;   // jf = bt, M2 = 64
    float4 x0 = D[PHI(f0)],       x1 = D[PHI(f0 + 64)];
    float4 x2 = D[PHI(f0 + 128)], x3 = D[PHI(f0 + 192)];
    float4 wA  = tw4[128 + f0];
    float4 wB0 = tw4[f0];
    float4 wB1 = tw4[64 + f0];
    float4 t1 = qmulc(x1, wA), t3 = qmulc(x3, wA);
    float4 u0 = qadd(x0, t1), u1 = qsub(x0, t1);
    float4 u2 = qadd(x2, t3), u3 = qsub(x2, t3);
    float4 s2 = qmulc(u2, wB0), s3 = qmulc(u3, wB1);
    D[PHI(f0 + 64)]  = qadd(u1, s3);
    D[PHI(f0 + 128)] = qsub(u0, s2);
}

// ---- legacy single-array radix-2 FFTs (fallback path only) ------------------
__device__ void fft512_dif(float2* d, const float2* twS, int t) {
    int off = 0;
    #pragma unroll
    for (int m = 256; m >= 1; m >>= 1) {
        if (m >= 64) __syncthreads();
        else __builtin_amdgcn_wave_barrier();
        int j = t & (m - 1);
        int p = ((t & ~(m - 1)) << 1) | j;
        int q = p + m;
        float2 a = d[p], b = d[q];
        d[p] = make_float2(a.x + b.x, a.y + b.y);
        float2 s = make_float2(a.x - b.x, a.y - b.y);
        d[q] = cmul(s, twS[off + j]);
        off += m;
    }
    __syncthreads();
}
__device__ void ifft512_dit(float2* d, const float2* twS, int t) {
    int off = 510;
    #pragma unroll
    for (int m = 1; m <= 256; m <<= 1) {
        if (m == 1 || m >= 128) __syncthreads();
        else __builtin_amdgcn_wave_barrier();
        int j = t & (m - 1);
        int p = ((t & ~(m - 1)) << 1) | j;
        int q = p + m;
        float2 w = twS[off + j];
        w.y = -w.y;
        float2 b = cmul(d[q], w);
        float2 a = d[p];
        d[p] = make_float2(a.x + b.x, a.y + b.y);
        d[q] = make_float2(a.x - b.x, a.y - b.y);
        off -= (m << 1);
    }
    __syncthreads();
}

// ---- zero a float range of out ---------------------------------------------
__global__ __launch_bounds__(256)
void zeroF(float* outf, int base) {
    outf[(size_t)base + blockIdx.x * 256 + threadIdx.x] = 0.f;
}

// ===========================================================================
// FAST PATH. P holds nspan*60 half-planes [nl][c][a]; Krev is the
// bit-reversed-w fp16 kernel copy.
// ===========================================================================

// R: Krev[p][h][jw] = K[p][h][brev9(jw)], p = b*5+a. grid(25*512).
__global__ __launch_bounds__(256)
void kernelR(const float* __restrict__ kr, const float* __restrict__ ki,
             h2* Krev) {
    int p = blockIdx.x >> 9;
    int h = blockIdx.x & 511;
    int t = threadIdx.x;
    size_t base = ((size_t)p * G_ + h) * G_;
    int j0 = __brev((unsigned)t) >> 23;
    int j1 = __brev((unsigned)(t + 256)) >> 23;
    st2(Krev, base + t,       make_float2(kr[base + j0], ki[base + j0]));
    st2(Krev, base + t + 256, make_float2(kr[base + j1], ki[base + j1]));
}

// A2: block = (nl,c,oct); loops a=0..4. NEW load mapping: thread t owns row
// h=t and the full 8-wide wc strip -> x loads are 4x float4 per a (was 16
// scalar); mps hoisted once as 4x float4. Values and LDS cells identical to
// the scalar version; FFT/store phases unchanged. grid(nspan*12*32), 256 thr.
__global__ __launch_bounds__(256)
void kernelA2(const float* __restrict__ xr, const float* __restrict__ xi,
              const float* __restrict__ mr, const float* __restrict__ mi,
              h2* P, int n0, int nspan) {
    int blk = blockIdx.x;
    int oct = blk & 31;
    int rest = blk >> 5;
    int c  = rest % 12;
    int nl = rest / 12;
    int n  = n0 + nl;
    int t = threadIdx.x;
    __shared__ float2 twS[512];
    __shared__ float4 rows4[8][262];
    build_twS(twS, t);
    const float4* tw4 = (const float4*)twS;

    int wc0 = oct * 8;
    // hoist mps row segment (8 re + 8 im), thread t owns h = t
    size_t mrow = ((size_t)c * H_ + t) * H_ + wc0;
    float4 mR0 = *(const float4*)&mr[mrow];
    float4 mR1 = *(const float4*)&mr[mrow + 4];
    float4 mI0 = *(const float4*)&mi[mrow];
    float4 mI1 = *(const float4*)&mi[mrow + 4];

    int r = t & 7;
    int wv = t >> 6, ln = t & 63;
    float4* d0 = &rows4[2 * wv][0];
    float4* d1 = &rows4[2 * wv + 1][0];
    int e = t + 128;
    int pos = 2 * PHI(e >> 1) + (e & 1);   // f2 index within a row

    for (int a = 0; a < 5; a++) {
        size_t xrow = (((size_t)n * A_ + a) * H_ + t) * H_ + wc0;
        float4 xR0 = *(const float4*)&xr[xrow];
        float4 xR1 = *(const float4*)&xr[xrow + 4];
        float4 xI0 = *(const float4*)&xi[xrow];
        float4 xI1 = *(const float4*)&xi[xrow + 4];
        // write 8 wc columns into their rows at position e = h+128
        // (pad zeros never written: fwd_quad0 never reads them)
        #define EMITA2(j, xre, xim, mre, mim) \
            ((float2*)&rows4[j][0])[pos] = \
                make_float2((xre) * (mre) - (xim) * (mim), \
                            (xre) * (mim) + (xim) * (mre))
        EMITA2(0, xR0.x, xI0.x, mR0.x, mI0.x);
        EMITA2(1, xR0.y, xI0.y, mR0.y, mI0.y);
        EMITA2(2, xR0.z, xI0.z, mR0.z, mI0.z);
        EMITA2(3, xR0.w, xI0.w, mR0.w, mI0.w);
        EMITA2(4, xR1.x, xI1.x, mR1.x, mI1.x);
        EMITA2(5, xR1.y, xI1.y, mR1.y, mI1.y);
        EMITA2(6, xR1.z, xI1.z, mR1.z, mI1.z);
        EMITA2(7, xR1.w, xI1.w, mR1.w, mI1.w);
        #undef EMITA2
        __syncthreads();

        fwd_quad0(d0, tw4, ln);         fwd_quad0(d1, tw4, ln);
        __builtin_amdgcn_wave_barrier();
        fwd_quad(d0, tw4, ln, 16, 192); fwd_quad(d1, tw4, ln, 16, 192);
        __builtin_amdgcn_wave_barrier();
        fwd_quad(d0, tw4, ln, 4, 240);  fwd_quad(d1, tw4, ln, 4, 240);
        __builtin_amdgcn_wave_barrier();
        fwd_quad(d0, tw4, ln, 1, 252);  fwd_quad(d1, tw4, ln, 1, 252);
        __syncthreads();

        h2* Pp = P + (size_t)((nl * 12 + c) * 5 + a) * IMGC_;
        #pragma unroll
        for (int k = 0; k < 16; k++) {
            int jh = k * 32 + (t >> 3);
            float4 v = rows4[r][PHI(jh >> 1)];
            float2 res = (jh & 1) ? make_float2(v.x - v.z, v.y - v.w)
                                  : make_float2(v.x + v.z, v.y + v.w);
            st2(Pp, (size_t)jh * 256 + oct * 8 + r, res);
        }
        __syncthreads();   // store reads done before next a's pad writes
    }
}

// B2: 320 thr, wave w owns array a=w (load, fwd FFT) and b=w (inv FFT, store);
// mix is pointwise per f4-column -> in-place, 4 syncthreads total.
// grid 8 XCD chunks x (64 jh x 12 c x nspan). (PROVEN form — untouched.)
__global__ __launch_bounds__(320)
void kernelB2(const h2* __restrict__ Krev, h2* P, int nspan) {
    int blk = blockIdx.x;
    int xcd = blk & 7;
    int idx = blk >> 3;
    int cn  = 12 * nspan;
    int jh  = xcd * 64 + idx / cn;
    int rem = idx % cn;
    int c   = rem % 12;
    int nl  = rem / 12;
    int htrue = __brev((unsigned)jh) >> 23;
    int t = threadIdx.x;
    __shared__ float2 twS[512];
    __shared__ float4 Fa4[5][256];
    build_twS(twS, t);
    const float4* tw4 = (const float4*)twS;
    int wv = t >> 6, ln = t & 63;
    size_t pbase = (size_t)((nl * 12 + c) * 5) * IMGC_ + (size_t)jh * 256;

    // wave w loads array a=w (centered pad in w-dim; zeros never written)
    float2* Ff2 = (float2*)&Fa4[wv][0];
    const h2* Pa = P + pbase + (size_t)wv * IMGC_;
    #pragma unroll
    for (int k = 0; k < 4; k++) {
        int e = ln + 64 * k;
        float2 v = ld2(Pa, e);
        int ec = e + 128;
        Ff2[2 * PHI(ec >> 1) + (ec & 1)] = v;
    }
    __builtin_amdgcn_wave_barrier();

    float4* D = &Fa4[wv][0];
    fwd_quad0(D, tw4, ln);         __builtin_amdgcn_wave_barrier();
    fwd_quad(D, tw4, ln, 16, 192); __builtin_amdgcn_wave_barrier();
    fwd_quad(D, tw4, ln, 4, 240);  __builtin_amdgcn_wave_barrier();
    fwd_quad(D, tw4, ln, 1, 252);
    __syncthreads();   // all 5 arrays' forward FFTs done

    if (t < 256) {
        // fused fwd mm=1 on read: F[2t] = e0+e1, F[2t+1] = e0-e1
        float2 f0[5], f1[5];
        #pragma unroll
        for (int a = 0; a < 5; a++) {
            float4 x = Fa4[a][PHI(t)];
            f0[a] = make_float2(x.x + x.z, x.y + x.w);
            f1[a] = make_float2(x.x - x.z, x.y - x.w);
        }
        const h2x2* Kp = reinterpret_cast<const h2x2*>(Krev);
        #pragma unroll
        for (int b = 0; b < 5; b++) {
            float2 a0 = make_float2(0.f, 0.f);
            float2 a1 = make_float2(0.f, 0.f);
            #pragma unroll
            for (int a = 0; a < 5; a++) {
                h2x2 kv = Kp[((size_t)(b * 5 + a) * G_ + htrue) * 256 + t];
                float k0x = (float)kv.x0, k0y = (float)kv.y0;
                float k1x = (float)kv.x1, k1y = (float)kv.y1;
                a0.x += k0x * f0[a].x - k0y * f0[a].y;
                a0.y += k0x * f0[a].y + k0y * f0[a].x;
                a1.x += k1x * f1[a].x - k1y * f1[a].y;
                a1.y += k1x * f1[a].y + k1y * f1[a].x;
            }
            // fused inv mm=1 on write: (a0+a1, a0-a1) in place over Fa
            Fa4[b][PHI(t)] =
                make_float4(a0.x + a1.x, a0.y + a1.y, a0.x - a1.x, a0.y - a1.y);
        }
    }
    __syncthreads();   // mix writes visible

    inv_quad(D, tw4, ln, 1, 254, 252);  __builtin_amdgcn_wave_barrier();
    inv_quad(D, tw4, ln, 4, 248, 240);  __builtin_amdgcn_wave_barrier();
    inv_quad(D, tw4, ln, 16, 224, 192); __builtin_amdgcn_wave_barrier();
    inv_quad_crop(D, tw4, ln);          // only crop window written
    __builtin_amdgcn_wave_barrier();

    // wave w stores b=w (crop w-dim)
    h2* Pb = P + pbase + (size_t)wv * IMGC_;
    #pragma unroll
    for (int k = 0; k < 4; k++) {
        int e = ln + 64 * k;
        int ec = e + 128;
        float2 v = Ff2[2 * PHI(ec >> 1) + (ec & 1)];
        st2(Pb, e, v);
    }
}

// C2: block = (nl,b,oct,cg); loops 3 c's of group cg. NEW load mapping:
// thread t owns jh-pair (2t,2t+1) x 8 wc -> P loads are 4x 16B vectors per c
// (was 16 scalar); fused DIT mm=1 values land in the same rows4 cells.
// FFT/readout/atomic phases unchanged. grid(nspan*5*32*NCG_), 256 thr.
__global__ __launch_bounds__(256)
void kernelC2(const float* __restrict__ mr, const float* __restrict__ mi,
              const h2* __restrict__ P, float* outf, int n0, int nspan) {
    int blk = blockIdx.x;
    int oct = blk & 31;
    int b   = (blk >> 5) % 5;
    int rest = blk / 160;
    int cg = rest % NCG_;
    int nl = rest / NCG_;
    int n  = n0 + nl;
    int t = threadIdx.x;
    __shared__ float2 twS[512];
    __shared__ float4 rows4[8][262];
    build_twS(twS, t);
    const float4* tw4 = (const float4*)twS;

    int r = t & 7;
    int wc0 = oct * 8;
    int wc = wc0 + r;
    int wv = t >> 6, ln = t & 63;
    float4* d0 = &rows4[2 * wv][0];
    float4* d1 = &rows4[2 * wv + 1][0];
    const float2* rowf2 = (const float2*)&rows4[r][0];
    int pp = PHI(t);

    float acc[8];
    #pragma unroll
    for (int k = 0; k < 8; k++) acc[k] = 0.f;

    for (int ci = 0; ci < 3; ci++) {
        int c = cg * 3 + ci;
        const h2* Pb = P + (size_t)((nl * 12 + c) * 5 + b) * IMGC_;
        {
            int jh0 = 2 * t;
            const h2x4* q0 =
                reinterpret_cast<const h2x4*>(&Pb[(size_t)jh0 * 256 + wc0]);
            const h2x4* q1 =
                reinterpret_cast<const h2x4*>(&Pb[(size_t)(jh0 + 1) * 256 + wc0]);
            h2x4 A0 = q0[0], A1 = q0[1];
            h2x4 B0 = q1[0], B1 = q1[1];
            // fused DIT mm=1: (p0+p1, p0-p1) per wc column j
            #define FUSEC2(j, ax, ay, bx, by) \
                rows4[j][pp] = make_float4((float)(ax) + (float)(bx), \
                                           (float)(ay) + (float)(by), \
                                           (float)(ax) - (float)(bx), \
                                           (float)(ay) - (float)(by))
            FUSEC2(0, A0.x0, A0.y0, B0.x0, B0.y0);
            FUSEC2(1, A0.x1, A0.y1, B0.x1, B0.y1);
            FUSEC2(2, A0.x2, A0.y2, B0.x2, B0.y2);
            FUSEC2(3, A0.x3, A0.y3, B0.x3, B0.y3);
            FUSEC2(4, A1.x0, A1.y0, B1.x0, B1.y0);
            FUSEC2(5, A1.x1, A1.y1, B1.x1, B1.y1);
            FUSEC2(6, A1.x2, A1.y2, B1.x2, B1.y2);
            FUSEC2(7, A1.x3, A1.y3, B1.x3, B1.y3);
            #undef FUSEC2
        }
        __syncthreads();

        inv_quad(d0, tw4, ln, 1, 254, 252);  inv_quad(d1, tw4, ln, 1, 254, 252);
        __builtin_amdgcn_wave_barrier();
        inv_quad(d0, tw4, ln, 4, 248, 240);  inv_quad(d1, tw4, ln, 4, 248, 240);
        __builtin_amdgcn_wave_barrier();
        inv_quad(d0, tw4, ln, 16, 224, 192); inv_quad(d1, tw4, ln, 16, 224, 192);
        __builtin_amdgcn_wave_barrier();
        inv_quad_crop(d0, tw4, ln);          inv_quad_crop(d1, tw4, ln);
        __syncthreads();

        #pragma unroll
        for (int k = 0; k < 8; k++) {
            int hh = (t >> 3) + 32 * k;
            int e = hh + 128;
            float2 v = rowf2[2 * PHI(e >> 1) + (e & 1)];
            size_t mo = (((size_t)c) * H_ + hh) * H_ + wc;
            acc[k] += mr[mo] * v.x + mi[mo] * v.y;
        }
        __syncthreads();   // readout done before next c's load writes
    }

    #pragma unroll
    for (int k = 0; k < 8; k++) {
        int hh = (t >> 3) + 32 * k;
        size_t idx = (((size_t)n * A_ + b) * H_ + hh) * H_ + wc;
        unsafeAtomicAdd(&outf[idx], acc[k] * SCALE_);
    }
}

// ===========================================================================
// FALLBACK PATH (used when ws_size < 57.7 MB)
// ===========================================================================

__global__ __launch_bounds__(256)
void kernelA(const float* __restrict__ xr, const float* __restrict__ xi,
             const float* __restrict__ mr, const float* __restrict__ mi,
             h2* X1, int n, int c, int a) {
    int oct = blockIdx.x;
    int t = threadIdx.x;
    __shared__ float2 twS[512];
    __shared__ float2 rows[8][516];
    build_twS(twS, t);

    int r = t & 7;
    int wc = oct * 8 + r;
    #pragma unroll
    for (int k = 0; k < 8; k++) {
        int h = (t >> 3) + 32 * k;
        size_t xo = (((size_t)n * A_ + a) * H_ + h) * H_ + wc;
        size_t mo = (((size_t)c) * H_ + h) * H_ + wc;
        float xr_ = xr[xo], xi_ = xi[xo];
        float mr_ = mr[mo], mi_ = mi[mo];
        rows[r][h + 128] = make_float2(xr_ * mr_ - xi_ * mi_,
                                       xr_ * mi_ + xi_ * mr_);
        rows[r][(h < 128) ? h : (h + 256)] = make_float2(0.f, 0.f);
    }
    __syncthreads();
    for (int rr = 0; rr < 8; rr++) fft512_dif(&rows[rr][0], twS, t);

    #pragma unroll
    for (int k = 0; k < 16; k++) {
        int jh = k * 32 + (t >> 3);
        st2(X1, (size_t)jh * 256 + oct * 8 + (t & 7), rows[t & 7][jh]);
    }
}

__global__ __launch_bounds__(256)
void kernelB(const float* __restrict__ kr, const float* __restrict__ ki,
             const h2* X1, h2* X2, int b, int a) {
    int jh = blockIdx.x;
    int htrue = __brev((unsigned)jh) >> 23;
    int t = threadIdx.x;
    __shared__ float2 twS[512];
    __shared__ float2 F[512];
    __shared__ float2 g[512];
    build_twS(twS, t);

    float2 v = ld2(X1, (size_t)jh * 256 + t);
    F[t + 128] = v;
    F[(t < 128) ? t : (t + 256)] = make_float2(0.f, 0.f);
    __syncthreads();
    fft512_dif(F, twS, t);

    #pragma unroll
    for (int half = 0; half < 2; half++) {
        int jw = t + half * 256;
        int wtrue = __brev((unsigned)jw) >> 23;
        size_t kidx = (((size_t)(b * A_ + a)) * G_ + htrue) * G_ + wtrue;
        g[jw] = cmul(make_float2(kr[kidx], ki[kidx]), F[jw]);
    }
    ifft512_dit(g, twS, t);

    float2 res = g[t + 128];
    size_t o = (size_t)jh * 256 + t;
    if (a == 0) st2(X2, o, res);
    else {
        float2 cur = ld2(X2, o);
        st2(X2, o, make_float2(cur.x + res.x, cur.y + res.y));
    }
}

__global__ __launch_bounds__(256)
void kernelC(const float* __restrict__ mr, const float* __restrict__ mi,
             const h2* X2, float* outf, int n, int c, int b) {
    int oct = blockIdx.x;
    int t = threadIdx.x;
    __shared__ float2 twS[512];
    __shared__ float2 rows[8][516];
    build_twS(twS, t);

    #pragma unroll
    for (int k = 0; k < 16; k++) {
        int jh = k * 32 + (t >> 3);
        rows[t & 7][jh] = ld2(X2, (size_t)jh * 256 + oct * 8 + (t & 7));
    }
    for (int rr = 0; rr < 8; rr++) ifft512_dit(&rows[rr][0], twS, t);

    int r = t & 7;
    int wc = oct * 8 + r;
    #pragma unroll
    for (int k = 0; k < 8; k++) {
        int hh = (t >> 3) + 32 * k;
        float2 v = rows[r][hh + 128];
        size_t mo = (((size_t)c) * H_ + hh) * H_ + wc;
        float m_r = mr[mo], m_i = mi[mo];
        float re = (m_r * v.x + m_i * v.y) * SCALE_;
        size_t idx = (((size_t)n * A_ + b) * H_ + hh) * H_ + wc;
        outf[idx] += re;
    }
}

// ===========================================================================
extern "C" void kernel_launch(void* const* d_in, const int* in_sizes, int n_in,
                              void* d_out, int out_size, void* d_ws, size_t ws_size,
                              hipStream_t stream) {
    const float* xr = (const float*)d_in[0];
    const float* xi = (const float*)d_in[1];
    const float* mr = (const float*)d_in[2];
    const float* mi = (const float*)d_in[3];
    const float* kr = (const float*)d_in[4];
    const float* ki = (const float*)d_in[5];
    float* outf = (float*)d_out;
    (void)in_sizes; (void)n_in; (void)out_size;

    const size_t KREV_BYTES = 25ull * G_ * G_ * sizeof(h2);    // 26,214,400
    const size_t PLANES1    = 60ull * IMGC_ * sizeof(h2);      // 31,457,280
    const size_t PLANES2    = 120ull * IMGC_ * sizeof(h2);     // 62,914,560

    if (d_ws != nullptr && ws_size >= PLANES2 + KREV_BYTES) {
        // ---- fully fused: both n in every dispatch (5 dispatches total)
        h2* P    = (h2*)d_ws;
        h2* Krev = (h2*)((char*)d_ws + PLANES2);
        zeroF<<<OUTF_ / 256, 256, 0, stream>>>(outf, 0);
        kernelR<<<25 * 512, 256, 0, stream>>>(kr, ki, Krev);
        kernelA2<<<2 * C_ * 32, 256, 0, stream>>>(xr, xi, mr, mi, P, 0, 2);
        kernelB2<<<2 * C_ * 512, 320, 0, stream>>>(Krev, P, 2);
        kernelC2<<<2 * A_ * 32 * NCG_, 256, 0, stream>>>(mr, mi, P, outf, 0, 2);
        return;
    }

    if (d_ws != nullptr && ws_size >= PLANES1 + KREV_BYTES) {
        // ---- per-n schedule
        h2* P    = (h2*)d_ws;
        h2* Krev = (h2*)((char*)d_ws + PLANES1);
        zeroF<<<OUTF_ / 256, 256, 0, stream>>>(outf, 0);
        kernelR<<<25 * 512, 256, 0, stream>>>(kr, ki, Krev);
        for (int n = 0; n < N_; n++) {
            kernelA2<<<C_ * 32, 256, 0, stream>>>(xr, xi, mr, mi, P, n, 1);
            kernelB2<<<C_ * 512, 320, 0, stream>>>(Krev, P, 1);
            kernelC2<<<A_ * 32 * NCG_, 256, 0, stream>>>(mr, mi, P, outf, n, 1);
        }
        return;
    }

    // ---- fallback ----
    zeroF<<<HALFF_ / 256, 256, 0, stream>>>(outf, 0);
    {
        h2* X1 = (h2*)(outf + HALFF_);
        h2* X2 = (h2*)(outf + HALFF_ + IMGC_);
        for (int c = 0; c < C_; c++)
            for (int b = 0; b < A_; b++) {
                for (int a = 0; a < A_; a++) {
                    kernelA<<<32, 256, 0, stream>>>(xr, xi, mr, mi, X1, 0, c, a);
                    kernelB<<<512, 256, 0, stream>>>(kr, ki, X1, X2, b, a);
                }
                kernelC<<<32, 256, 0, stream>>>(mr, mi, X2, outf, 0, c, b);
            }
    }

    zeroF<<<HALFF_ / 256, 256, 0, stream>>>(outf, HALFF_);
    {
        h2* X1 = (h2*)d_in[0];
        h2* X2 = (h2*)d_in[1];
        for (int c = 0; c < C_; c++)
            for (int b = 0; b < A_; b++) {
                for (int a = 0; a < A_; a++) {
                    kernelA<<<32, 256, 0, stream>>>(xr, xi, mr, mi, X1, 1, c, a);
                    kernelB<<<512, 256, 0, stream>>>(kr, ki, X1, X2, b, a);
                }
                kernelC<<<32, 256, 0, stream>>>(mr, mi, X2, outf, 1, c, b);
            }
    }
}